// Round 22
// baseline (823.723 us; speedup 1.0000x reference)
//
#include <hip/hip_runtime.h>
#include <math.h>

#define N_NODES 50000
#define N_EDGES 600000
#define H 128
#define G_GRAPHS 100
#define C_CLS 10
#define NBLK_SCAN ((N_NODES + 255) / 256)
#define RSUB 16

// ---------------- graph segment structure (batch sorted -> boundary detect) ----------------

__global__ void fill2_kernel(float* __restrict__ p, float* __restrict__ q, float v, int n) {
    int i = blockIdx.x * 256 + threadIdx.x;
    if (i < n) { p[i] = v; q[i] = v; }
}

__global__ void starts_kernel(const int* __restrict__ batch, int* __restrict__ starts, int n) {
    int i = blockIdx.x * 256 + threadIdx.x;
    if (i >= n) return;
    int b = batch[i];
    int prev = (i == 0) ? -1 : batch[i - 1];
    for (int g = prev + 1; g <= b; ++g) starts[g] = i;
    if (i == n - 1) {
        for (int g = b + 1; g < G_GRAPHS; ++g) starts[g] = n;
    }
}

__global__ void counts_kernel(const int* __restrict__ starts, int* __restrict__ counts) {
    int g = threadIdx.x;
    if (g < G_GRAPHS) {
        int e = (g == G_GRAPHS - 1) ? N_NODES : starts[g + 1];
        counts[g] = e - starts[g];
    }
}

// ---------------- CSR build (dst-grouped, deterministic) ----------------

__global__ void indeg_kernel(const int* __restrict__ dst, int* __restrict__ indeg, int ne) {
    int e = blockIdx.x * 256 + threadIdx.x;
    if (e < ne) atomicAdd(&indeg[dst[e]], 1);
}

__global__ void bsum_kernel(const int* __restrict__ indeg, int* __restrict__ bsum, int n) {
    __shared__ int red[256];
    int i = blockIdx.x * 256 + threadIdx.x;
    red[threadIdx.x] = (i < n) ? indeg[i] : 0;
    __syncthreads();
    for (int o = 128; o > 0; o >>= 1) {
        if (threadIdx.x < o) red[threadIdx.x] += red[threadIdx.x + o];
        __syncthreads();
    }
    if (threadIdx.x == 0) bsum[blockIdx.x] = red[0];
}

__global__ void bscan_kernel(const int* __restrict__ bsum, int* __restrict__ boff, int nb) {
    __shared__ int s[256];
    int t = threadIdx.x;
    s[t] = (t < nb) ? bsum[t] : 0;
    __syncthreads();
    for (int o = 1; o < 256; o <<= 1) {
        int v = (t >= o) ? s[t - o] : 0;
        __syncthreads();
        s[t] += v;
        __syncthreads();
    }
    if (t < nb) boff[t] = (t == 0) ? 0 : s[t - 1];
}

__global__ void rowptr_kernel(const int* __restrict__ indeg, const int* __restrict__ boff,
                              int* __restrict__ rowptr, int n) {
    __shared__ int s[256];
    int i = blockIdx.x * 256 + threadIdx.x;
    int t = threadIdx.x;
    int v = (i < n) ? indeg[i] : 0;
    s[t] = v;
    __syncthreads();
    for (int o = 1; o < 256; o <<= 1) {
        int u = (t >= o) ? s[t - o] : 0;
        __syncthreads();
        s[t] += u;
        __syncthreads();
    }
    int incl = s[t];
    int excl = incl - v;
    if (i < n) rowptr[i] = boff[blockIdx.x] + excl;
    if (i == n - 1) rowptr[n] = boff[blockIdx.x] + incl;
}

__global__ void scatter_kernel(const int* __restrict__ src, const int* __restrict__ dst,
                               const int* __restrict__ rowptr, int* __restrict__ cursor,
                               int* __restrict__ srcC, int ne) {
    int e = blockIdx.x * 256 + threadIdx.x;
    if (e >= ne) return;
    int d = dst[e];
    int pos = rowptr[d] + atomicAdd(&cursor[d], 1);
    srcC[pos] = src[e];
}

// ---------------- wave-per-node odd-even sort (canonical ascending; deterministic) ----------

__global__ __launch_bounds__(256) void wsort_kernel(const int* __restrict__ rowptr,
                                                    int* __restrict__ srcC, int n) {
    int node = blockIdx.x * 4 + (threadIdx.x >> 6);
    if (node >= n) return;
    int lane = threadIdx.x & 63;
    int e0 = rowptr[node], e1 = rowptr[node + 1];
    int len = e1 - e0;
    if (len <= 1) return;
    if (len <= 64) {
        int key = (lane < len) ? srcC[e0 + lane] : 0x7fffffff;
        for (int p = 0; p < len; ++p) {
            int partner = ((lane ^ p) & 1) ? lane - 1 : lane + 1;
            int pv = __shfl(key, partner & 63, 64);
            if (partner >= 0 && partner < 64) {
                key = (partner > lane) ? min(key, pv) : max(key, pv);
            }
        }
        if (lane < len) srcC[e0 + lane] = key;
    } else {
        if (lane == 0) {
            for (int i = e0 + 1; i < e1; ++i) {
                int k = srcC[i];
                int j = i - 1;
                while (j >= e0 && srcC[j] > k) { srcC[j + 1] = srcC[j]; --j; }
                srcC[j + 1] = k;
            }
        }
    }
}

// ---------------- degree / norm ----------------
// Block 0 (mask all-ones): deg = indeg + 1 exactly -> coalesced, no gather.

__global__ void degnorm0_kernel(const int* __restrict__ indeg, float* __restrict__ norm,
                                float* __restrict__ mnorm, int n) {
    int d = blockIdx.x * 256 + threadIdx.x;
    if (d >= n) return;
    float nd = rsqrtf(1.f + (float)indeg[d]);
    norm[d] = nd;
    mnorm[d] = nd;
}

__global__ void degnorm_kernel(const int* __restrict__ rowptr, const int* __restrict__ srcC,
                               const float* __restrict__ mask, float* __restrict__ norm,
                               float* __restrict__ mnorm, int n) {
    int idx = blockIdx.x * 256 + threadIdx.x;
    int d = idx >> 3;
    if (d >= n) return;
    int l = idx & 7;
    float md = mask[d];
    float s = 0.f;
    if (md != 0.f) {
        int e0 = rowptr[d], e1 = rowptr[d + 1];
        for (int e = e0 + l; e < e1; e += 8) s += mask[srcC[e]];
    }
#pragma unroll
    for (int o = 4; o > 0; o >>= 1) s += __shfl_down(s, o, 8);
    if (l == 0) {
        float nd = rsqrtf(1.f + md * s);
        norm[d] = nd;
        mnorm[d] = md * nd;
    }
}

// ---------------- GEMM (full): out[n][128] = (gfac[n] * A[n][128]) @ W[128][128] ----------------

__global__ __launch_bounds__(256) void gemm128_kernel(const float* __restrict__ A,
                                                      const float* __restrict__ W,
                                                      const float* __restrict__ gf,
                                                      float* __restrict__ out, int nrows) {
    __shared__ float sT[128][68];
    int row0 = blockIdx.x * 64;
    int tid = threadIdx.x;
    for (int i = tid; i < 2048; i += 256) {
        int r = i >> 5, c4 = i & 31;
        int row = row0 + r;
        float4 v = make_float4(0.f, 0.f, 0.f, 0.f);
        if (row < nrows) {
            float g = gf[row];
            v = ((const float4*)(A + (size_t)row * H))[c4];
            v.x *= g; v.y *= g; v.z *= g; v.w *= g;
        }
        sT[c4 * 4 + 0][r] = v.x; sT[c4 * 4 + 1][r] = v.y;
        sT[c4 * 4 + 2][r] = v.z; sT[c4 * 4 + 3][r] = v.w;
    }
    __syncthreads();
    int cg = tid & 31;
    int rg = tid >> 5;
    float acc[8][4];
#pragma unroll
    for (int i = 0; i < 8; ++i)
#pragma unroll
        for (int j = 0; j < 4; ++j) acc[i][j] = 0.f;

#pragma unroll 4
    for (int k = 0; k < 128; ++k) {
        float4 w4 = ((const float4*)(W + k * H))[cg];
        const float4* pa = (const float4*)(&sT[k][rg * 8]);
        float4 a0 = pa[0], a1 = pa[1];
        float av[8] = {a0.x, a0.y, a0.z, a0.w, a1.x, a1.y, a1.z, a1.w};
#pragma unroll
        for (int i = 0; i < 8; ++i) {
            acc[i][0] = fmaf(av[i], w4.x, acc[i][0]);
            acc[i][1] = fmaf(av[i], w4.y, acc[i][1]);
            acc[i][2] = fmaf(av[i], w4.z, acc[i][2]);
            acc[i][3] = fmaf(av[i], w4.w, acc[i][3]);
        }
    }
#pragma unroll
    for (int i = 0; i < 8; ++i) {
        int row = row0 + rg * 8 + i;
        if (row < nrows) {
            float4 o = make_float4(acc[i][0], acc[i][1], acc[i][2], acc[i][3]);
            ((float4*)(out + (size_t)row * H))[cg] = o;
        }
    }
}

// ---------------- GEMM (compacted rows): only active-list rows; per-row math identical ------

__global__ __launch_bounds__(256) void gemm128c_kernel(const float* __restrict__ A,
                                                       const float* __restrict__ W,
                                                       const float* __restrict__ gf,
                                                       const int* __restrict__ alist,
                                                       const int* __restrict__ alcnt,
                                                       float* __restrict__ out) {
    int nact = *alcnt;
    int row0 = blockIdx.x * 64;
    if (row0 >= nact) return;
    __shared__ float sT[128][68];
    __shared__ int ridx[64];
    int tid = threadIdx.x;
    if (tid < 64) ridx[tid] = (row0 + tid < nact) ? alist[row0 + tid] : -1;
    __syncthreads();
    for (int i = tid; i < 2048; i += 256) {
        int r = i >> 5, c4 = i & 31;
        int row = ridx[r];
        float4 v = make_float4(0.f, 0.f, 0.f, 0.f);
        if (row >= 0) {
            float g = gf[row];
            v = ((const float4*)(A + (size_t)row * H))[c4];
            v.x *= g; v.y *= g; v.z *= g; v.w *= g;
        }
        sT[c4 * 4 + 0][r] = v.x; sT[c4 * 4 + 1][r] = v.y;
        sT[c4 * 4 + 2][r] = v.z; sT[c4 * 4 + 3][r] = v.w;
    }
    __syncthreads();
    int cg = tid & 31;
    int rg = tid >> 5;
    float acc[8][4];
#pragma unroll
    for (int i = 0; i < 8; ++i)
#pragma unroll
        for (int j = 0; j < 4; ++j) acc[i][j] = 0.f;

#pragma unroll 4
    for (int k = 0; k < 128; ++k) {
        float4 w4 = ((const float4*)(W + k * H))[cg];
        const float4* pa = (const float4*)(&sT[k][rg * 8]);
        float4 a0 = pa[0], a1 = pa[1];
        float av[8] = {a0.x, a0.y, a0.z, a0.w, a1.x, a1.y, a1.z, a1.w};
#pragma unroll
        for (int i = 0; i < 8; ++i) {
            acc[i][0] = fmaf(av[i], w4.x, acc[i][0]);
            acc[i][1] = fmaf(av[i], w4.y, acc[i][1]);
            acc[i][2] = fmaf(av[i], w4.z, acc[i][2]);
            acc[i][3] = fmaf(av[i], w4.w, acc[i][3]);
        }
    }
#pragma unroll
    for (int i = 0; i < 8; ++i) {
        int row = ridx[rg * 8 + i];
        if (row >= 0) {
            float4 o = make_float4(acc[i][0], acc[i][1], acc[i][2], acc[i][3]);
            ((float4*)(out + (size_t)row * H))[cg] = o;
        }
    }
}

// ---------------- fused gather agg + self + bias + relu + score-dot ----------------

template <bool GUARD>
__global__ __launch_bounds__(256) void agg_fused_kernel(const float* __restrict__ xw,
        const int* __restrict__ rowptr, const int* __restrict__ srcC,
        const float* __restrict__ mask, const float* __restrict__ norm,
        const float* __restrict__ mnorm,
        const float* __restrict__ b, const float* __restrict__ Ws,
        float* __restrict__ hout, float* __restrict__ xws, int n) {
    int node = blockIdx.x * 8 + (threadIdx.x >> 5);
    if (node >= n) return;
    int t = threadIdx.x & 31;
    const float4* xw4 = (const float4*)xw;
    float md = mask[node];
    float nd = norm[node];
    float4 a0 = make_float4(0.f, 0.f, 0.f, 0.f);
    float4 a1 = a0, a2 = a0, a3 = a0;
    if (md != 0.f) {
        int e0 = rowptr[node], e1 = rowptr[node + 1];
        int e = e0;
        for (; e + 3 < e1; e += 4) {
            int s0 = srcC[e], s1 = srcC[e + 1], s2 = srcC[e + 2], s3 = srcC[e + 3];
            float c0 = mnorm[s0];
            float c1 = mnorm[s1];
            float c2 = mnorm[s2];
            float c3 = mnorm[s3];
            if (!GUARD || c0 != 0.f) {
                float4 v = xw4[(size_t)s0 * 32 + t];
                a0.x = fmaf(v.x, c0, a0.x); a0.y = fmaf(v.y, c0, a0.y);
                a0.z = fmaf(v.z, c0, a0.z); a0.w = fmaf(v.w, c0, a0.w);
            }
            if (!GUARD || c1 != 0.f) {
                float4 v = xw4[(size_t)s1 * 32 + t];
                a1.x = fmaf(v.x, c1, a1.x); a1.y = fmaf(v.y, c1, a1.y);
                a1.z = fmaf(v.z, c1, a1.z); a1.w = fmaf(v.w, c1, a1.w);
            }
            if (!GUARD || c2 != 0.f) {
                float4 v = xw4[(size_t)s2 * 32 + t];
                a2.x = fmaf(v.x, c2, a2.x); a2.y = fmaf(v.y, c2, a2.y);
                a2.z = fmaf(v.z, c2, a2.z); a2.w = fmaf(v.w, c2, a2.w);
            }
            if (!GUARD || c3 != 0.f) {
                float4 v = xw4[(size_t)s3 * 32 + t];
                a3.x = fmaf(v.x, c3, a3.x); a3.y = fmaf(v.y, c3, a3.y);
                a3.z = fmaf(v.z, c3, a3.z); a3.w = fmaf(v.w, c3, a3.w);
            }
        }
        for (; e < e1; ++e) {
            int s = srcC[e];
            float c = mnorm[s];
            if (!GUARD || c != 0.f) {
                float4 v = xw4[(size_t)s * 32 + t];
                a0.x = fmaf(v.x, c, a0.x); a0.y = fmaf(v.y, c, a0.y);
                a0.z = fmaf(v.z, c, a0.z); a0.w = fmaf(v.w, c, a0.w);
            }
        }
        float sc = md * nd;
        a0.x = (((a0.x + a1.x) + a2.x) + a3.x) * sc;
        a0.y = (((a0.y + a1.y) + a2.y) + a3.y) * sc;
        a0.z = (((a0.z + a1.z) + a2.z) + a3.z) * sc;
        a0.w = (((a0.w + a1.w) + a2.w) + a3.w) * sc;
    }
    float4 self = xw4[(size_t)node * 32 + t];
    float4 bb = ((const float4*)b)[t];
    float n2 = nd * nd;
    float4 v;
    v.x = fmaxf(fmaf(self.x, n2, a0.x) + bb.x, 0.f);
    v.y = fmaxf(fmaf(self.y, n2, a0.y) + bb.y, 0.f);
    v.z = fmaxf(fmaf(self.z, n2, a0.z) + bb.z, 0.f);
    v.w = fmaxf(fmaf(self.w, n2, a0.w) + bb.w, 0.f);
    ((float4*)hout)[(size_t)node * 32 + t] = v;
    // fused score projection: xws[node] = dot(hout_row, Ws)
    float4 w = ((const float4*)Ws)[t];
    float p = ((v.x * w.x + v.y * w.y) + v.z * w.z) + v.w * w.w;
#pragma unroll
    for (int o = 16; o > 0; o >>= 1) p += __shfl_down(p, o, 32);
    if (t == 0) xws[node] = p;
}

// ---------------- score gather: 8 lanes per node -> masked score ----------------

__global__ void score_gather_kernel(const int* __restrict__ rowptr, const int* __restrict__ srcC,
        const float* __restrict__ xws, const float* __restrict__ mask,
        const float* __restrict__ norm, const float* __restrict__ mnorm,
        const float* __restrict__ bs, float* __restrict__ scorem, int n) {
    int idx = blockIdx.x * 256 + threadIdx.x;
    int d = idx >> 3;
    if (d >= n) return;
    int l = idx & 7;
    float md = mask[d];
    float nd = norm[d];
    float acc = 0.f;
    if (md != 0.f) {
        int e0 = rowptr[d], e1 = rowptr[d + 1];
        for (int e = e0 + l; e < e1; e += 8) {
            int s = srcC[e];
            float c = mnorm[s];
            if (c != 0.f) acc = fmaf(xws[s], c, acc);
        }
    }
#pragma unroll
    for (int o = 4; o > 0; o >>= 1) acc += __shfl_down(acc, o, 8);
    if (l == 0) {
        float out;
        if (md != 0.f) out = acc * (md * nd) + xws[d] * nd * nd + bs[0];
        else out = -INFINITY;
        scorem[d] = out;
    }
}

// ---------------- rank-based top-k (kk + compact fused): one 64-lane wave per node ----------

__global__ __launch_bounds__(256) void rank_kernel(const float* __restrict__ scorem,
        const float* __restrict__ mask, const int* __restrict__ batch,
        const int* __restrict__ starts, const int* __restrict__ counts,
        float* __restrict__ nmask, float* __restrict__ gfac,
        int* __restrict__ alist, int* __restrict__ alcnt, int docompact, int n) {
    int i = blockIdx.x * 4 + (threadIdx.x >> 6);
    if (i >= n) return;
    int lane = threadIdx.x & 63;
    float sci = scorem[i];
    if (sci == -INFINITY) {
        if (lane == 0) { nmask[i] = 0.f; gfac[i] = 0.f; }
        return;
    }
    int g = batch[i];
    int s0 = starts[g], cnt = counts[g];
    int r = 0, act = 0;
    for (int j = lane; j < cnt; j += 64) {
        float sj = scorem[s0 + j];
        if (sj != -INFINITY) {
            ++act;
            if (sj > sci || (sj == sci && (s0 + j) < i)) ++r;
        }
    }
#pragma unroll
    for (int o = 32; o > 0; o >>= 1) {
        r += __shfl_down(r, o);
        act += __shfl_down(act, o);
    }
    if (lane == 0) {
        int kk = (int)ceilf(0.5f * (float)act);
        bool keep = (r < kk);
        float m = mask[i];
        nmask[i] = keep ? m : 0.f;
        gfac[i] = keep ? tanhf(sci) * m : 0.f;
        if (docompact && keep && m > 0.f) {
            int pos = atomicAdd(alcnt, 1);
            alist[pos] = i;
        }
    }
}

// ---------------- readout phase 1: per-(graph, sub-slice) partials ----------------

__global__ __launch_bounds__(128) void readout_part_kernel(const float* __restrict__ h,
        const float* __restrict__ mask, const float* __restrict__ gfac,
        const int* __restrict__ starts, const int* __restrict__ counts,
        float* __restrict__ partS, float* __restrict__ partM, float* __restrict__ partC) {
    int g = blockIdx.x >> 4;
    int sub = blockIdx.x & (RSUB - 1);
    int f = threadIdx.x;
    int s0 = starts[g], cnt = counts[g];
    float s = 0.f, mx = -INFINITY, c = 0.f;
    for (int i = sub; i < cnt; i += RSUB) {
        float m = mask[s0 + i];
        if (m > 0.f) {
            float v = h[(size_t)(s0 + i) * H + f] * gfac[s0 + i];
            s += v; mx = fmaxf(mx, v); c += 1.f;
        }
    }
    size_t pidx = (size_t)blockIdx.x * H + f;
    partS[pidx] = s;
    partM[pidx] = mx;
    if (f == 0) partC[blockIdx.x] = c;
}

// ---------------- readout phase 2: combine partials in fixed order -> rbuf ----------------

__global__ __launch_bounds__(128) void readout_comb_kernel(const float* __restrict__ partS,
        const float* __restrict__ partM, const float* __restrict__ partC,
        float* __restrict__ r) {
    int g = blockIdx.x;
    int f = threadIdx.x;
    float S = 0.f, M = -INFINITY, C = 0.f;
    for (int sub = 0; sub < RSUB; ++sub) {
        size_t pidx = (size_t)(g * RSUB + sub) * H + f;
        S += partS[pidx];
        M = fmaxf(M, partM[pidx]);
        C += partC[g * RSUB + sub];
    }
    float mean = S / fmaxf(C, 1.f);
    if (C == 0.f) M = 0.f;
    r[(size_t)g * 2 * H + f] += M;
    r[(size_t)g * 2 * H + H + f] += mean;
}

// ---------------- MLP head + log_softmax ----------------

__global__ __launch_bounds__(128) void mlp_kernel(const float* __restrict__ r,
        const float* __restrict__ Wl1, const float* __restrict__ bl1,
        const float* __restrict__ Wl2, const float* __restrict__ bl2,
        const float* __restrict__ Wl3, const float* __restrict__ bl3,
        float* __restrict__ out) {
    int g = blockIdx.x;
    int t = threadIdx.x;
    __shared__ float sz[256];
    __shared__ float sy1[128];
    __shared__ float sy2[64];
    __shared__ float sy3[10];
    __shared__ float sred[2];
    sz[t] = r[g * 256 + t];
    sz[t + 128] = r[g * 256 + 128 + t];
    __syncthreads();
    float a = bl1[t];
    for (int k = 0; k < 256; ++k) a = fmaf(sz[k], Wl1[k * 128 + t], a);
    sy1[t] = fmaxf(a, 0.f);
    __syncthreads();
    if (t < 64) {
        float a2 = bl2[t];
        for (int k = 0; k < 128; ++k) a2 = fmaf(sy1[k], Wl2[k * 64 + t], a2);
        sy2[t] = fmaxf(a2, 0.f);
    }
    __syncthreads();
    if (t < 10) {
        float a3 = bl3[t];
        for (int k = 0; k < 64; ++k) a3 = fmaf(sy2[k], Wl3[k * 10 + t], a3);
        sy3[t] = a3;
    }
    __syncthreads();
    if (t == 0) {
        float m = sy3[0];
        for (int c2 = 1; c2 < 10; ++c2) m = fmaxf(m, sy3[c2]);
        float se = 0.f;
        for (int c2 = 0; c2 < 10; ++c2) se += expf(sy3[c2] - m);
        sred[0] = m; sred[1] = logf(se);
    }
    __syncthreads();
    if (t < 10) out[g * 10 + t] = sy3[t] - sred[0] - sred[1];
}

// ---------------- launch ----------------

extern "C" void kernel_launch(void* const* d_in, const int* in_sizes, int n_in,
                              void* d_out, int out_size, void* d_ws, size_t ws_size,
                              hipStream_t stream) {
    const float* x     = (const float*)d_in[0];
    const int*   ei    = (const int*)d_in[1];
    const int*   batch = (const int*)d_in[2];
    const int* src  = ei;
    const int* dstp = ei + N_EDGES;
    const float* Wb[3]  = {(const float*)d_in[3], (const float*)d_in[7],  (const float*)d_in[11]};
    const float* bbv[3] = {(const float*)d_in[4], (const float*)d_in[8],  (const float*)d_in[12]};
    const float* Wsb[3] = {(const float*)d_in[5], (const float*)d_in[9],  (const float*)d_in[13]};
    const float* bsb[3] = {(const float*)d_in[6], (const float*)d_in[10], (const float*)d_in[14]};
    const float* Wl1 = (const float*)d_in[15];
    const float* bl1 = (const float*)d_in[16];
    const float* Wl2 = (const float*)d_in[17];
    const float* bl2 = (const float*)d_in[18];
    const float* Wl3 = (const float*)d_in[19];
    const float* bl3 = (const float*)d_in[20];
    float* out = (float*)d_out;

    // workspace carve (4B units)
    float* fws = (float*)d_ws;
    size_t off = 0;
    float* hA     = fws + off; off += (size_t)N_NODES * H;
    float* hB     = fws + off; off += (size_t)N_NODES * H;
    float* xw     = fws + off; off += (size_t)N_NODES * H;
    float* scorem = fws + off; off += N_NODES;
    float* xws    = fws + off; off += N_NODES;
    float* norm   = fws + off; off += N_NODES;
    float* mnorm  = fws + off; off += N_NODES;
    float* mA     = fws + off; off += N_NODES;
    float* mB     = fws + off; off += N_NODES;
    float* gfac   = fws + off; off += N_NODES;
    float* rbuf   = fws + off; off += (size_t)G_GRAPHS * 2 * H;
    float* partS  = fws + off; off += (size_t)G_GRAPHS * RSUB * H;
    float* partM  = fws + off; off += (size_t)G_GRAPHS * RSUB * H;
    float* partC  = fws + off; off += (size_t)G_GRAPHS * RSUB;
    int* counts   = (int*)(fws + off); off += G_GRAPHS;
    int* starts   = (int*)(fws + off); off += G_GRAPHS;
    int* rowptr   = (int*)(fws + off); off += N_NODES + 1;
    int* indeg    = (int*)(fws + off); off += N_NODES;
    int* cursor   = (int*)(fws + off); off += N_NODES;
    int* bsum     = (int*)(fws + off); off += NBLK_SCAN;
    int* boff     = (int*)(fws + off); off += NBLK_SCAN;
    int* alist    = (int*)(fws + off); off += N_NODES;
    int* alcnt    = (int*)(fws + off); off += 1;
    int* srcC     = (int*)(fws + off); off += N_EDGES;

    int nblkN  = (N_NODES + 255) / 256;
    int nblkN8 = (N_NODES * 8 + 255) / 256;
    int nblkE  = (N_EDGES + 255) / 256;
    int nblkG  = (N_NODES + 63) / 64;

    // graph segment structure (batch is sorted -> boundary detect, no atomics)
    starts_kernel<<<nblkN, 256, 0, stream>>>(batch, starts, N_NODES);
    counts_kernel<<<1, 128, 0, stream>>>(starts, counts);

    // CSR build (dst-grouped), deterministic via per-node wave sort
    hipMemsetAsync(indeg, 0, N_NODES * sizeof(int), stream);
    hipMemsetAsync(cursor, 0, N_NODES * sizeof(int), stream);
    indeg_kernel<<<nblkE, 256, 0, stream>>>(dstp, indeg, N_EDGES);
    bsum_kernel<<<NBLK_SCAN, 256, 0, stream>>>(indeg, bsum, N_NODES);
    bscan_kernel<<<1, 256, 0, stream>>>(bsum, boff, NBLK_SCAN);
    rowptr_kernel<<<NBLK_SCAN, 256, 0, stream>>>(indeg, boff, rowptr, N_NODES);
    scatter_kernel<<<nblkE, 256, 0, stream>>>(src, dstp, rowptr, cursor, srcC, N_EDGES);
    wsort_kernel<<<(N_NODES + 3) / 4, 256, 0, stream>>>(rowptr, srcC, N_NODES);

    fill2_kernel<<<nblkN, 256, 0, stream>>>(mA, gfac, 1.f, N_NODES);
    hipMemsetAsync(rbuf, 0, G_GRAPHS * 2 * H * sizeof(float), stream);

    const float* hin = x;
    float* hout = hA;
    const float* mcur = mA;
    float* mnext = mB;

    for (int blk = 0; blk < 3; ++blk) {
        if (blk == 0) {
            degnorm0_kernel<<<nblkN, 256, 0, stream>>>(indeg, norm, mnorm, N_NODES);
            gemm128_kernel<<<nblkG, 256, 0, stream>>>(hin, Wb[blk], gfac, xw, N_NODES);
            agg_fused_kernel<false><<<(N_NODES + 7) / 8, 256, 0, stream>>>(
                xw, rowptr, srcC, mcur, norm, mnorm, bbv[blk], Wsb[blk], hout, xws, N_NODES);
        } else {
            degnorm_kernel<<<nblkN8, 256, 0, stream>>>(rowptr, srcC, mcur, norm, mnorm, N_NODES);
            gemm128c_kernel<<<nblkG, 256, 0, stream>>>(hin, Wb[blk], gfac, alist, alcnt, xw);
            agg_fused_kernel<true><<<(N_NODES + 7) / 8, 256, 0, stream>>>(
                xw, rowptr, srcC, mcur, norm, mnorm, bbv[blk], Wsb[blk], hout, xws, N_NODES);
        }
        score_gather_kernel<<<nblkN8, 256, 0, stream>>>(rowptr, srcC, xws, mcur, norm, mnorm,
                                                        bsb[blk], scorem, N_NODES);
        if (blk < 2) hipMemsetAsync(alcnt, 0, sizeof(int), stream);
        rank_kernel<<<(N_NODES + 3) / 4, 256, 0, stream>>>(scorem, mcur, batch, starts, counts,
                                                           mnext, gfac, alist, alcnt,
                                                           (blk < 2) ? 1 : 0, N_NODES);
        readout_part_kernel<<<G_GRAPHS * RSUB, 128, 0, stream>>>(hout, mnext, gfac, starts,
                                                                 counts, partS, partM, partC);
        readout_comb_kernel<<<G_GRAPHS, 128, 0, stream>>>(partS, partM, partC, rbuf);
        hin = hout;
        hout = (hout == hA) ? hB : hA;
        const float* tm = mcur; mcur = mnext; mnext = (float*)tm;
    }

    mlp_kernel<<<G_GRAPHS, 128, 0, stream>>>(rbuf, Wl1, bl1, Wl2, bl2, Wl3, bl3, out);
}

// Round 23
// 445.506 us; speedup vs baseline: 1.8490x; 1.8490x over previous
//
#include <hip/hip_runtime.h>
#include <math.h>

#define N_NODES 50000
#define N_EDGES 600000
#define H 128
#define G_GRAPHS 100
#define C_CLS 10
#define NBLK_SCAN ((N_NODES + 255) / 256)
#define RSUB 16

// ---------------- graph segment structure (batch sorted -> boundary detect) ----------------

__global__ void fill2_kernel(float* __restrict__ p, float* __restrict__ q, float v, int n) {
    int i = blockIdx.x * 256 + threadIdx.x;
    if (i < n) { p[i] = v; q[i] = v; }
}

__global__ void starts_kernel(const int* __restrict__ batch, int* __restrict__ starts, int n) {
    int i = blockIdx.x * 256 + threadIdx.x;
    if (i >= n) return;
    int b = batch[i];
    int prev = (i == 0) ? -1 : batch[i - 1];
    for (int g = prev + 1; g <= b; ++g) starts[g] = i;
    if (i == n - 1) {
        for (int g = b + 1; g < G_GRAPHS; ++g) starts[g] = n;
    }
}

__global__ void counts_kernel(const int* __restrict__ starts, int* __restrict__ counts) {
    int g = threadIdx.x;
    if (g < G_GRAPHS) {
        int e = (g == G_GRAPHS - 1) ? N_NODES : starts[g + 1];
        counts[g] = e - starts[g];
    }
}

// ---------------- CSR build (dst-grouped, deterministic) ----------------

__global__ void indeg_kernel(const int* __restrict__ dst, int* __restrict__ indeg, int ne) {
    int e = blockIdx.x * 256 + threadIdx.x;
    if (e < ne) atomicAdd(&indeg[dst[e]], 1);
}

__global__ void bsum_kernel(const int* __restrict__ indeg, int* __restrict__ bsum, int n) {
    __shared__ int red[256];
    int i = blockIdx.x * 256 + threadIdx.x;
    red[threadIdx.x] = (i < n) ? indeg[i] : 0;
    __syncthreads();
    for (int o = 128; o > 0; o >>= 1) {
        if (threadIdx.x < o) red[threadIdx.x] += red[threadIdx.x + o];
        __syncthreads();
    }
    if (threadIdx.x == 0) bsum[blockIdx.x] = red[0];
}

__global__ void bscan_kernel(const int* __restrict__ bsum, int* __restrict__ boff, int nb) {
    __shared__ int s[256];
    int t = threadIdx.x;
    s[t] = (t < nb) ? bsum[t] : 0;
    __syncthreads();
    for (int o = 1; o < 256; o <<= 1) {
        int v = (t >= o) ? s[t - o] : 0;
        __syncthreads();
        s[t] += v;
        __syncthreads();
    }
    if (t < nb) boff[t] = (t == 0) ? 0 : s[t - 1];
}

__global__ void rowptr_kernel(const int* __restrict__ indeg, const int* __restrict__ boff,
                              int* __restrict__ rowptr, int n) {
    __shared__ int s[256];
    int i = blockIdx.x * 256 + threadIdx.x;
    int t = threadIdx.x;
    int v = (i < n) ? indeg[i] : 0;
    s[t] = v;
    __syncthreads();
    for (int o = 1; o < 256; o <<= 1) {
        int u = (t >= o) ? s[t - o] : 0;
        __syncthreads();
        s[t] += u;
        __syncthreads();
    }
    int incl = s[t];
    int excl = incl - v;
    if (i < n) rowptr[i] = boff[blockIdx.x] + excl;
    if (i == n - 1) rowptr[n] = boff[blockIdx.x] + incl;
}

__global__ void scatter_kernel(const int* __restrict__ src, const int* __restrict__ dst,
                               const int* __restrict__ rowptr, int* __restrict__ cursor,
                               int* __restrict__ srcC, int ne) {
    int e = blockIdx.x * 256 + threadIdx.x;
    if (e >= ne) return;
    int d = dst[e];
    int pos = rowptr[d] + atomicAdd(&cursor[d], 1);
    srcC[pos] = src[e];
}

// ---------------- wave-per-node odd-even sort (canonical ascending; deterministic) ----------

__global__ __launch_bounds__(256) void wsort_kernel(const int* __restrict__ rowptr,
                                                    int* __restrict__ srcC, int n) {
    int node = blockIdx.x * 4 + (threadIdx.x >> 6);
    if (node >= n) return;
    int lane = threadIdx.x & 63;
    int e0 = rowptr[node], e1 = rowptr[node + 1];
    int len = e1 - e0;
    if (len <= 1) return;
    if (len <= 64) {
        int key = (lane < len) ? srcC[e0 + lane] : 0x7fffffff;
        for (int p = 0; p < len; ++p) {
            int partner = ((lane ^ p) & 1) ? lane - 1 : lane + 1;
            int pv = __shfl(key, partner & 63, 64);
            if (partner >= 0 && partner < 64) {
                key = (partner > lane) ? min(key, pv) : max(key, pv);
            }
        }
        if (lane < len) srcC[e0 + lane] = key;
    } else {
        if (lane == 0) {
            for (int i = e0 + 1; i < e1; ++i) {
                int k = srcC[i];
                int j = i - 1;
                while (j >= e0 && srcC[j] > k) { srcC[j + 1] = srcC[j]; --j; }
                srcC[j + 1] = k;
            }
        }
    }
}

// ---------------- degree / norm ----------------
// Block 0 (mask all-ones): deg = indeg + 1 exactly -> coalesced, no gather.

__global__ void degnorm0_kernel(const int* __restrict__ indeg, float* __restrict__ norm,
                                float* __restrict__ mnorm, int n) {
    int d = blockIdx.x * 256 + threadIdx.x;
    if (d >= n) return;
    float nd = rsqrtf(1.f + (float)indeg[d]);
    norm[d] = nd;
    mnorm[d] = nd;
}

__global__ void degnorm_kernel(const int* __restrict__ rowptr, const int* __restrict__ srcC,
                               const float* __restrict__ mask, float* __restrict__ norm,
                               float* __restrict__ mnorm, int n) {
    int idx = blockIdx.x * 256 + threadIdx.x;
    int d = idx >> 3;
    if (d >= n) return;
    int l = idx & 7;
    float md = mask[d];
    float s = 0.f;
    if (md != 0.f) {
        int e0 = rowptr[d], e1 = rowptr[d + 1];
        for (int e = e0 + l; e < e1; e += 8) s += mask[srcC[e]];
    }
#pragma unroll
    for (int o = 4; o > 0; o >>= 1) s += __shfl_down(s, o, 8);
    if (l == 0) {
        float nd = rsqrtf(1.f + md * s);
        norm[d] = nd;
        mnorm[d] = md * nd;
    }
}

// ---------------- active-node compaction (all lanes same-address -> wave-coalesced atomics) --

__global__ void compact_kernel(const float* __restrict__ nmask, int* __restrict__ alist,
                               int* __restrict__ alcnt, int n) {
    int i = blockIdx.x * 256 + threadIdx.x;
    if (i < n && nmask[i] > 0.f) {
        int pos = atomicAdd(alcnt, 1);
        alist[pos] = i;
    }
}

// ---------------- GEMM (full): out[n][128] = (gfac[n] * A[n][128]) @ W[128][128] ----------------

__global__ __launch_bounds__(256) void gemm128_kernel(const float* __restrict__ A,
                                                      const float* __restrict__ W,
                                                      const float* __restrict__ gf,
                                                      float* __restrict__ out, int nrows) {
    __shared__ float sT[128][68];
    int row0 = blockIdx.x * 64;
    int tid = threadIdx.x;
    for (int i = tid; i < 2048; i += 256) {
        int r = i >> 5, c4 = i & 31;
        int row = row0 + r;
        float4 v = make_float4(0.f, 0.f, 0.f, 0.f);
        if (row < nrows) {
            float g = gf[row];
            v = ((const float4*)(A + (size_t)row * H))[c4];
            v.x *= g; v.y *= g; v.z *= g; v.w *= g;
        }
        sT[c4 * 4 + 0][r] = v.x; sT[c4 * 4 + 1][r] = v.y;
        sT[c4 * 4 + 2][r] = v.z; sT[c4 * 4 + 3][r] = v.w;
    }
    __syncthreads();
    int cg = tid & 31;
    int rg = tid >> 5;
    float acc[8][4];
#pragma unroll
    for (int i = 0; i < 8; ++i)
#pragma unroll
        for (int j = 0; j < 4; ++j) acc[i][j] = 0.f;

#pragma unroll 4
    for (int k = 0; k < 128; ++k) {
        float4 w4 = ((const float4*)(W + k * H))[cg];
        const float4* pa = (const float4*)(&sT[k][rg * 8]);
        float4 a0 = pa[0], a1 = pa[1];
        float av[8] = {a0.x, a0.y, a0.z, a0.w, a1.x, a1.y, a1.z, a1.w};
#pragma unroll
        for (int i = 0; i < 8; ++i) {
            acc[i][0] = fmaf(av[i], w4.x, acc[i][0]);
            acc[i][1] = fmaf(av[i], w4.y, acc[i][1]);
            acc[i][2] = fmaf(av[i], w4.z, acc[i][2]);
            acc[i][3] = fmaf(av[i], w4.w, acc[i][3]);
        }
    }
#pragma unroll
    for (int i = 0; i < 8; ++i) {
        int row = row0 + rg * 8 + i;
        if (row < nrows) {
            float4 o = make_float4(acc[i][0], acc[i][1], acc[i][2], acc[i][3]);
            ((float4*)(out + (size_t)row * H))[cg] = o;
        }
    }
}

// ---------------- GEMM (compacted rows): only active-list rows; per-row math identical ------

__global__ __launch_bounds__(256) void gemm128c_kernel(const float* __restrict__ A,
                                                       const float* __restrict__ W,
                                                       const float* __restrict__ gf,
                                                       const int* __restrict__ alist,
                                                       const int* __restrict__ alcnt,
                                                       float* __restrict__ out) {
    int nact = *alcnt;
    int row0 = blockIdx.x * 64;
    if (row0 >= nact) return;
    __shared__ float sT[128][68];
    __shared__ int ridx[64];
    int tid = threadIdx.x;
    if (tid < 64) ridx[tid] = (row0 + tid < nact) ? alist[row0 + tid] : -1;
    __syncthreads();
    for (int i = tid; i < 2048; i += 256) {
        int r = i >> 5, c4 = i & 31;
        int row = ridx[r];
        float4 v = make_float4(0.f, 0.f, 0.f, 0.f);
        if (row >= 0) {
            float g = gf[row];
            v = ((const float4*)(A + (size_t)row * H))[c4];
            v.x *= g; v.y *= g; v.z *= g; v.w *= g;
        }
        sT[c4 * 4 + 0][r] = v.x; sT[c4 * 4 + 1][r] = v.y;
        sT[c4 * 4 + 2][r] = v.z; sT[c4 * 4 + 3][r] = v.w;
    }
    __syncthreads();
    int cg = tid & 31;
    int rg = tid >> 5;
    float acc[8][4];
#pragma unroll
    for (int i = 0; i < 8; ++i)
#pragma unroll
        for (int j = 0; j < 4; ++j) acc[i][j] = 0.f;

#pragma unroll 4
    for (int k = 0; k < 128; ++k) {
        float4 w4 = ((const float4*)(W + k * H))[cg];
        const float4* pa = (const float4*)(&sT[k][rg * 8]);
        float4 a0 = pa[0], a1 = pa[1];
        float av[8] = {a0.x, a0.y, a0.z, a0.w, a1.x, a1.y, a1.z, a1.w};
#pragma unroll
        for (int i = 0; i < 8; ++i) {
            acc[i][0] = fmaf(av[i], w4.x, acc[i][0]);
            acc[i][1] = fmaf(av[i], w4.y, acc[i][1]);
            acc[i][2] = fmaf(av[i], w4.z, acc[i][2]);
            acc[i][3] = fmaf(av[i], w4.w, acc[i][3]);
        }
    }
#pragma unroll
    for (int i = 0; i < 8; ++i) {
        int row = ridx[rg * 8 + i];
        if (row >= 0) {
            float4 o = make_float4(acc[i][0], acc[i][1], acc[i][2], acc[i][3]);
            ((float4*)(out + (size_t)row * H))[cg] = o;
        }
    }
}

// ---------------- fused gather agg + self + bias + relu + score-dot ----------------

template <bool GUARD>
__global__ __launch_bounds__(256) void agg_fused_kernel(const float* __restrict__ xw,
        const int* __restrict__ rowptr, const int* __restrict__ srcC,
        const float* __restrict__ mask, const float* __restrict__ norm,
        const float* __restrict__ mnorm,
        const float* __restrict__ b, const float* __restrict__ Ws,
        float* __restrict__ hout, float* __restrict__ xws, int n) {
    int node = blockIdx.x * 8 + (threadIdx.x >> 5);
    if (node >= n) return;
    int t = threadIdx.x & 31;
    const float4* xw4 = (const float4*)xw;
    float md = mask[node];
    float nd = norm[node];
    float4 a0 = make_float4(0.f, 0.f, 0.f, 0.f);
    float4 a1 = a0, a2 = a0, a3 = a0;
    if (md != 0.f) {
        int e0 = rowptr[node], e1 = rowptr[node + 1];
        int e = e0;
        for (; e + 3 < e1; e += 4) {
            int s0 = srcC[e], s1 = srcC[e + 1], s2 = srcC[e + 2], s3 = srcC[e + 3];
            float c0 = mnorm[s0];
            float c1 = mnorm[s1];
            float c2 = mnorm[s2];
            float c3 = mnorm[s3];
            if (!GUARD || c0 != 0.f) {
                float4 v = xw4[(size_t)s0 * 32 + t];
                a0.x = fmaf(v.x, c0, a0.x); a0.y = fmaf(v.y, c0, a0.y);
                a0.z = fmaf(v.z, c0, a0.z); a0.w = fmaf(v.w, c0, a0.w);
            }
            if (!GUARD || c1 != 0.f) {
                float4 v = xw4[(size_t)s1 * 32 + t];
                a1.x = fmaf(v.x, c1, a1.x); a1.y = fmaf(v.y, c1, a1.y);
                a1.z = fmaf(v.z, c1, a1.z); a1.w = fmaf(v.w, c1, a1.w);
            }
            if (!GUARD || c2 != 0.f) {
                float4 v = xw4[(size_t)s2 * 32 + t];
                a2.x = fmaf(v.x, c2, a2.x); a2.y = fmaf(v.y, c2, a2.y);
                a2.z = fmaf(v.z, c2, a2.z); a2.w = fmaf(v.w, c2, a2.w);
            }
            if (!GUARD || c3 != 0.f) {
                float4 v = xw4[(size_t)s3 * 32 + t];
                a3.x = fmaf(v.x, c3, a3.x); a3.y = fmaf(v.y, c3, a3.y);
                a3.z = fmaf(v.z, c3, a3.z); a3.w = fmaf(v.w, c3, a3.w);
            }
        }
        for (; e < e1; ++e) {
            int s = srcC[e];
            float c = mnorm[s];
            if (!GUARD || c != 0.f) {
                float4 v = xw4[(size_t)s * 32 + t];
                a0.x = fmaf(v.x, c, a0.x); a0.y = fmaf(v.y, c, a0.y);
                a0.z = fmaf(v.z, c, a0.z); a0.w = fmaf(v.w, c, a0.w);
            }
        }
        float sc = md * nd;
        a0.x = (((a0.x + a1.x) + a2.x) + a3.x) * sc;
        a0.y = (((a0.y + a1.y) + a2.y) + a3.y) * sc;
        a0.z = (((a0.z + a1.z) + a2.z) + a3.z) * sc;
        a0.w = (((a0.w + a1.w) + a2.w) + a3.w) * sc;
    }
    float4 self = xw4[(size_t)node * 32 + t];
    float4 bb = ((const float4*)b)[t];
    float n2 = nd * nd;
    float4 v;
    v.x = fmaxf(fmaf(self.x, n2, a0.x) + bb.x, 0.f);
    v.y = fmaxf(fmaf(self.y, n2, a0.y) + bb.y, 0.f);
    v.z = fmaxf(fmaf(self.z, n2, a0.z) + bb.z, 0.f);
    v.w = fmaxf(fmaf(self.w, n2, a0.w) + bb.w, 0.f);
    ((float4*)hout)[(size_t)node * 32 + t] = v;
    // fused score projection: xws[node] = dot(hout_row, Ws)
    float4 w = ((const float4*)Ws)[t];
    float p = ((v.x * w.x + v.y * w.y) + v.z * w.z) + v.w * w.w;
#pragma unroll
    for (int o = 16; o > 0; o >>= 1) p += __shfl_down(p, o, 32);
    if (t == 0) xws[node] = p;
}

// ---------------- score gather: 8 lanes per node -> masked score ----------------

__global__ void score_gather_kernel(const int* __restrict__ rowptr, const int* __restrict__ srcC,
        const float* __restrict__ xws, const float* __restrict__ mask,
        const float* __restrict__ norm, const float* __restrict__ mnorm,
        const float* __restrict__ bs, float* __restrict__ scorem, int n) {
    int idx = blockIdx.x * 256 + threadIdx.x;
    int d = idx >> 3;
    if (d >= n) return;
    int l = idx & 7;
    float md = mask[d];
    float nd = norm[d];
    float acc = 0.f;
    if (md != 0.f) {
        int e0 = rowptr[d], e1 = rowptr[d + 1];
        for (int e = e0 + l; e < e1; e += 8) {
            int s = srcC[e];
            float c = mnorm[s];
            if (c != 0.f) acc = fmaf(xws[s], c, acc);
        }
    }
#pragma unroll
    for (int o = 4; o > 0; o >>= 1) acc += __shfl_down(acc, o, 8);
    if (l == 0) {
        float out;
        if (md != 0.f) out = acc * (md * nd) + xws[d] * nd * nd + bs[0];
        else out = -INFINITY;
        scorem[d] = out;
    }
}

// ---------------- rank-based top-k (kk fused): one 64-lane wave per node ----------------

__global__ __launch_bounds__(256) void rank_kernel(const float* __restrict__ scorem,
        const float* __restrict__ mask, const int* __restrict__ batch,
        const int* __restrict__ starts, const int* __restrict__ counts,
        float* __restrict__ nmask, float* __restrict__ gfac, int n) {
    int i = blockIdx.x * 4 + (threadIdx.x >> 6);
    if (i >= n) return;
    int lane = threadIdx.x & 63;
    float sci = scorem[i];
    if (sci == -INFINITY) {
        if (lane == 0) { nmask[i] = 0.f; gfac[i] = 0.f; }
        return;
    }
    int g = batch[i];
    int s0 = starts[g], cnt = counts[g];
    int r = 0, act = 0;
    for (int j = lane; j < cnt; j += 64) {
        float sj = scorem[s0 + j];
        if (sj != -INFINITY) {
            ++act;
            if (sj > sci || (sj == sci && (s0 + j) < i)) ++r;
        }
    }
#pragma unroll
    for (int o = 32; o > 0; o >>= 1) {
        r += __shfl_down(r, o);
        act += __shfl_down(act, o);
    }
    if (lane == 0) {
        int kk = (int)ceilf(0.5f * (float)act);
        bool keep = (r < kk);
        float m = mask[i];
        nmask[i] = keep ? m : 0.f;
        gfac[i] = keep ? tanhf(sci) * m : 0.f;
    }
}

// ---------------- readout phase 1: per-(graph, sub-slice) partials ----------------

__global__ __launch_bounds__(128) void readout_part_kernel(const float* __restrict__ h,
        const float* __restrict__ mask, const float* __restrict__ gfac,
        const int* __restrict__ starts, const int* __restrict__ counts,
        float* __restrict__ partS, float* __restrict__ partM, float* __restrict__ partC) {
    int g = blockIdx.x >> 4;
    int sub = blockIdx.x & (RSUB - 1);
    int f = threadIdx.x;
    int s0 = starts[g], cnt = counts[g];
    float s = 0.f, mx = -INFINITY, c = 0.f;
    for (int i = sub; i < cnt; i += RSUB) {
        float m = mask[s0 + i];
        if (m > 0.f) {
            float v = h[(size_t)(s0 + i) * H + f] * gfac[s0 + i];
            s += v; mx = fmaxf(mx, v); c += 1.f;
        }
    }
    size_t pidx = (size_t)blockIdx.x * H + f;
    partS[pidx] = s;
    partM[pidx] = mx;
    if (f == 0) partC[blockIdx.x] = c;
}

// ---------------- readout phase 2: combine partials in fixed order -> rbuf ----------------

__global__ __launch_bounds__(128) void readout_comb_kernel(const float* __restrict__ partS,
        const float* __restrict__ partM, const float* __restrict__ partC,
        float* __restrict__ r) {
    int g = blockIdx.x;
    int f = threadIdx.x;
    float S = 0.f, M = -INFINITY, C = 0.f;
    for (int sub = 0; sub < RSUB; ++sub) {
        size_t pidx = (size_t)(g * RSUB + sub) * H + f;
        S += partS[pidx];
        M = fmaxf(M, partM[pidx]);
        C += partC[g * RSUB + sub];
    }
    float mean = S / fmaxf(C, 1.f);
    if (C == 0.f) M = 0.f;
    r[(size_t)g * 2 * H + f] += M;
    r[(size_t)g * 2 * H + H + f] += mean;
}

// ---------------- MLP head + log_softmax ----------------

__global__ __launch_bounds__(128) void mlp_kernel(const float* __restrict__ r,
        const float* __restrict__ Wl1, const float* __restrict__ bl1,
        const float* __restrict__ Wl2, const float* __restrict__ bl2,
        const float* __restrict__ Wl3, const float* __restrict__ bl3,
        float* __restrict__ out) {
    int g = blockIdx.x;
    int t = threadIdx.x;
    __shared__ float sz[256];
    __shared__ float sy1[128];
    __shared__ float sy2[64];
    __shared__ float sy3[10];
    __shared__ float sred[2];
    sz[t] = r[g * 256 + t];
    sz[t + 128] = r[g * 256 + 128 + t];
    __syncthreads();
    float a = bl1[t];
    for (int k = 0; k < 256; ++k) a = fmaf(sz[k], Wl1[k * 128 + t], a);
    sy1[t] = fmaxf(a, 0.f);
    __syncthreads();
    if (t < 64) {
        float a2 = bl2[t];
        for (int k = 0; k < 128; ++k) a2 = fmaf(sy1[k], Wl2[k * 64 + t], a2);
        sy2[t] = fmaxf(a2, 0.f);
    }
    __syncthreads();
    if (t < 10) {
        float a3 = bl3[t];
        for (int k = 0; k < 64; ++k) a3 = fmaf(sy2[k], Wl3[k * 10 + t], a3);
        sy3[t] = a3;
    }
    __syncthreads();
    if (t == 0) {
        float m = sy3[0];
        for (int c2 = 1; c2 < 10; ++c2) m = fmaxf(m, sy3[c2]);
        float se = 0.f;
        for (int c2 = 0; c2 < 10; ++c2) se += expf(sy3[c2] - m);
        sred[0] = m; sred[1] = logf(se);
    }
    __syncthreads();
    if (t < 10) out[g * 10 + t] = sy3[t] - sred[0] - sred[1];
}

// ---------------- launch ----------------

extern "C" void kernel_launch(void* const* d_in, const int* in_sizes, int n_in,
                              void* d_out, int out_size, void* d_ws, size_t ws_size,
                              hipStream_t stream) {
    const float* x     = (const float*)d_in[0];
    const int*   ei    = (const int*)d_in[1];
    const int*   batch = (const int*)d_in[2];
    const int* src  = ei;
    const int* dstp = ei + N_EDGES;
    const float* Wb[3]  = {(const float*)d_in[3], (const float*)d_in[7],  (const float*)d_in[11]};
    const float* bbv[3] = {(const float*)d_in[4], (const float*)d_in[8],  (const float*)d_in[12]};
    const float* Wsb[3] = {(const float*)d_in[5], (const float*)d_in[9],  (const float*)d_in[13]};
    const float* bsb[3] = {(const float*)d_in[6], (const float*)d_in[10], (const float*)d_in[14]};
    const float* Wl1 = (const float*)d_in[15];
    const float* bl1 = (const float*)d_in[16];
    const float* Wl2 = (const float*)d_in[17];
    const float* bl2 = (const float*)d_in[18];
    const float* Wl3 = (const float*)d_in[19];
    const float* bl3 = (const float*)d_in[20];
    float* out = (float*)d_out;

    // workspace carve (4B units)
    float* fws = (float*)d_ws;
    size_t off = 0;
    float* hA     = fws + off; off += (size_t)N_NODES * H;
    float* hB     = fws + off; off += (size_t)N_NODES * H;
    float* xw     = fws + off; off += (size_t)N_NODES * H;
    float* scorem = fws + off; off += N_NODES;
    float* xws    = fws + off; off += N_NODES;
    float* norm   = fws + off; off += N_NODES;
    float* mnorm  = fws + off; off += N_NODES;
    float* mA     = fws + off; off += N_NODES;
    float* mB     = fws + off; off += N_NODES;
    float* gfac   = fws + off; off += N_NODES;
    float* rbuf   = fws + off; off += (size_t)G_GRAPHS * 2 * H;
    float* partS  = fws + off; off += (size_t)G_GRAPHS * RSUB * H;
    float* partM  = fws + off; off += (size_t)G_GRAPHS * RSUB * H;
    float* partC  = fws + off; off += (size_t)G_GRAPHS * RSUB;
    int* counts   = (int*)(fws + off); off += G_GRAPHS;
    int* starts   = (int*)(fws + off); off += G_GRAPHS;
    int* rowptr   = (int*)(fws + off); off += N_NODES + 1;
    int* indeg    = (int*)(fws + off); off += N_NODES;
    int* cursor   = (int*)(fws + off); off += N_NODES;
    int* bsum     = (int*)(fws + off); off += NBLK_SCAN;
    int* boff     = (int*)(fws + off); off += NBLK_SCAN;
    int* alist    = (int*)(fws + off); off += N_NODES;
    int* alcnt    = (int*)(fws + off); off += 1;
    int* srcC     = (int*)(fws + off); off += N_EDGES;

    int nblkN  = (N_NODES + 255) / 256;
    int nblkN8 = (N_NODES * 8 + 255) / 256;
    int nblkE  = (N_EDGES + 255) / 256;
    int nblkG  = (N_NODES + 63) / 64;

    // graph segment structure (batch is sorted -> boundary detect, no atomics)
    starts_kernel<<<nblkN, 256, 0, stream>>>(batch, starts, N_NODES);
    counts_kernel<<<1, 128, 0, stream>>>(starts, counts);

    // CSR build (dst-grouped), deterministic via per-node wave sort
    hipMemsetAsync(indeg, 0, N_NODES * sizeof(int), stream);
    hipMemsetAsync(cursor, 0, N_NODES * sizeof(int), stream);
    indeg_kernel<<<nblkE, 256, 0, stream>>>(dstp, indeg, N_EDGES);
    bsum_kernel<<<NBLK_SCAN, 256, 0, stream>>>(indeg, bsum, N_NODES);
    bscan_kernel<<<1, 256, 0, stream>>>(bsum, boff, NBLK_SCAN);
    rowptr_kernel<<<NBLK_SCAN, 256, 0, stream>>>(indeg, boff, rowptr, N_NODES);
    scatter_kernel<<<nblkE, 256, 0, stream>>>(src, dstp, rowptr, cursor, srcC, N_EDGES);
    wsort_kernel<<<(N_NODES + 3) / 4, 256, 0, stream>>>(rowptr, srcC, N_NODES);

    fill2_kernel<<<nblkN, 256, 0, stream>>>(mA, gfac, 1.f, N_NODES);
    hipMemsetAsync(rbuf, 0, G_GRAPHS * 2 * H * sizeof(float), stream);

    const float* hin = x;
    float* hout = hA;
    const float* mcur = mA;
    float* mnext = mB;

    for (int blk = 0; blk < 3; ++blk) {
        if (blk == 0) {
            degnorm0_kernel<<<nblkN, 256, 0, stream>>>(indeg, norm, mnorm, N_NODES);
            gemm128_kernel<<<nblkG, 256, 0, stream>>>(hin, Wb[blk], gfac, xw, N_NODES);
            agg_fused_kernel<false><<<(N_NODES + 7) / 8, 256, 0, stream>>>(
                xw, rowptr, srcC, mcur, norm, mnorm, bbv[blk], Wsb[blk], hout, xws, N_NODES);
        } else {
            degnorm_kernel<<<nblkN8, 256, 0, stream>>>(rowptr, srcC, mcur, norm, mnorm, N_NODES);
            gemm128c_kernel<<<nblkG, 256, 0, stream>>>(hin, Wb[blk], gfac, alist, alcnt, xw);
            agg_fused_kernel<true><<<(N_NODES + 7) / 8, 256, 0, stream>>>(
                xw, rowptr, srcC, mcur, norm, mnorm, bbv[blk], Wsb[blk], hout, xws, N_NODES);
        }
        score_gather_kernel<<<nblkN8, 256, 0, stream>>>(rowptr, srcC, xws, mcur, norm, mnorm,
                                                        bsb[blk], scorem, N_NODES);
        rank_kernel<<<(N_NODES + 3) / 4, 256, 0, stream>>>(scorem, mcur, batch, starts, counts,
                                                           mnext, gfac, N_NODES);
        if (blk < 2) {
            hipMemsetAsync(alcnt, 0, sizeof(int), stream);
            compact_kernel<<<nblkN, 256, 0, stream>>>(mnext, alist, alcnt, N_NODES);
        }
        readout_part_kernel<<<G_GRAPHS * RSUB, 128, 0, stream>>>(hout, mnext, gfac, starts,
                                                                 counts, partS, partM, partC);
        readout_comb_kernel<<<G_GRAPHS, 128, 0, stream>>>(partS, partM, partC, rbuf);
        hin = hout;
        hout = (hout == hA) ? hB : hA;
        const float* tm = mcur; mcur = mnext; mnext = (float*)tm;
    }

    mlp_kernel<<<G_GRAPHS, 128, 0, stream>>>(rbuf, Wl1, bl1, Wl2, bl2, Wl3, bl3, out);
}

// Round 24
// 426.801 us; speedup vs baseline: 1.9300x; 1.0438x over previous
//
#include <hip/hip_runtime.h>
#include <math.h>

#define N_NODES 50000
#define N_EDGES 600000
#define H 128
#define G_GRAPHS 100
#define C_CLS 10
#define NBLK_SCAN ((N_NODES + 255) / 256)
#define RSUB 16

// ---------------- combined init: segment starts + zero indeg/cursor + mask/gfac=1 ----------

__global__ void init_kernel(const int* __restrict__ batch, int* __restrict__ starts,
                            int* __restrict__ indeg, int* __restrict__ cursor,
                            float* __restrict__ mA, float* __restrict__ gfac, int n) {
    int i = blockIdx.x * 256 + threadIdx.x;
    if (i >= n) return;
    indeg[i] = 0;
    cursor[i] = 0;
    mA[i] = 1.f;
    gfac[i] = 1.f;
    int b = batch[i];
    int prev = (i == 0) ? -1 : batch[i - 1];
    for (int g = prev + 1; g <= b; ++g) starts[g] = i;
    if (i == n - 1) {
        for (int g = b + 1; g < G_GRAPHS; ++g) starts[g] = n;
    }
}

__global__ void counts_kernel(const int* __restrict__ starts, int* __restrict__ counts) {
    int g = threadIdx.x;
    if (g < G_GRAPHS) {
        int e = (g == G_GRAPHS - 1) ? N_NODES : starts[g + 1];
        counts[g] = e - starts[g];
    }
}

// ---------------- CSR build (dst-grouped, deterministic) ----------------

__global__ void indeg_kernel(const int* __restrict__ dst, int* __restrict__ indeg, int ne) {
    int e = blockIdx.x * 256 + threadIdx.x;
    if (e < ne) atomicAdd(&indeg[dst[e]], 1);
}

__global__ void bsum_kernel(const int* __restrict__ indeg, int* __restrict__ bsum, int n) {
    __shared__ int red[256];
    int i = blockIdx.x * 256 + threadIdx.x;
    red[threadIdx.x] = (i < n) ? indeg[i] : 0;
    __syncthreads();
    for (int o = 128; o > 0; o >>= 1) {
        if (threadIdx.x < o) red[threadIdx.x] += red[threadIdx.x + o];
        __syncthreads();
    }
    if (threadIdx.x == 0) bsum[blockIdx.x] = red[0];
}

__global__ void bscan_kernel(const int* __restrict__ bsum, int* __restrict__ boff, int nb) {
    __shared__ int s[256];
    int t = threadIdx.x;
    s[t] = (t < nb) ? bsum[t] : 0;
    __syncthreads();
    for (int o = 1; o < 256; o <<= 1) {
        int v = (t >= o) ? s[t - o] : 0;
        __syncthreads();
        s[t] += v;
        __syncthreads();
    }
    if (t < nb) boff[t] = (t == 0) ? 0 : s[t - 1];
}

__global__ void rowptr_kernel(const int* __restrict__ indeg, const int* __restrict__ boff,
                              int* __restrict__ rowptr, int n) {
    __shared__ int s[256];
    int i = blockIdx.x * 256 + threadIdx.x;
    int t = threadIdx.x;
    int v = (i < n) ? indeg[i] : 0;
    s[t] = v;
    __syncthreads();
    for (int o = 1; o < 256; o <<= 1) {
        int u = (t >= o) ? s[t - o] : 0;
        __syncthreads();
        s[t] += u;
        __syncthreads();
    }
    int incl = s[t];
    int excl = incl - v;
    if (i < n) rowptr[i] = boff[blockIdx.x] + excl;
    if (i == n - 1) rowptr[n] = boff[blockIdx.x] + incl;
}

__global__ void scatter_kernel(const int* __restrict__ src, const int* __restrict__ dst,
                               const int* __restrict__ rowptr, int* __restrict__ cursor,
                               int* __restrict__ srcC, int ne) {
    int e = blockIdx.x * 256 + threadIdx.x;
    if (e >= ne) return;
    int d = dst[e];
    int pos = rowptr[d] + atomicAdd(&cursor[d], 1);
    srcC[pos] = src[e];
}

// ---------------- wave-per-node odd-even sort (canonical ascending; deterministic) ----------

__global__ __launch_bounds__(256) void wsort_kernel(const int* __restrict__ rowptr,
                                                    int* __restrict__ srcC, int n) {
    int node = blockIdx.x * 4 + (threadIdx.x >> 6);
    if (node >= n) return;
    int lane = threadIdx.x & 63;
    int e0 = rowptr[node], e1 = rowptr[node + 1];
    int len = e1 - e0;
    if (len <= 1) return;
    if (len <= 64) {
        int key = (lane < len) ? srcC[e0 + lane] : 0x7fffffff;
        for (int p = 0; p < len; ++p) {
            int partner = ((lane ^ p) & 1) ? lane - 1 : lane + 1;
            int pv = __shfl(key, partner & 63, 64);
            if (partner >= 0 && partner < 64) {
                key = (partner > lane) ? min(key, pv) : max(key, pv);
            }
        }
        if (lane < len) srcC[e0 + lane] = key;
    } else {
        if (lane == 0) {
            for (int i = e0 + 1; i < e1; ++i) {
                int k = srcC[i];
                int j = i - 1;
                while (j >= e0 && srcC[j] > k) { srcC[j + 1] = srcC[j]; --j; }
                srcC[j + 1] = k;
            }
        }
    }
}

// ---------------- degree / norm ----------------

__global__ void degnorm0_kernel(const int* __restrict__ indeg, float* __restrict__ norm,
                                float* __restrict__ mnorm, int n) {
    int d = blockIdx.x * 256 + threadIdx.x;
    if (d >= n) return;
    float nd = rsqrtf(1.f + (float)indeg[d]);
    norm[d] = nd;
    mnorm[d] = nd;
}

__global__ void degnorm_kernel(const int* __restrict__ rowptr, const int* __restrict__ srcC,
                               const float* __restrict__ mask, float* __restrict__ norm,
                               float* __restrict__ mnorm, int n) {
    int idx = blockIdx.x * 256 + threadIdx.x;
    int d = idx >> 3;
    if (d >= n) return;
    int l = idx & 7;
    float md = mask[d];
    float s = 0.f;
    if (md != 0.f) {
        int e0 = rowptr[d], e1 = rowptr[d + 1];
        for (int e = e0 + l; e < e1; e += 8) s += mask[srcC[e]];
    }
#pragma unroll
    for (int o = 4; o > 0; o >>= 1) s += __shfl_down(s, o, 8);
    if (l == 0) {
        float nd = rsqrtf(1.f + md * s);
        norm[d] = nd;
        mnorm[d] = md * nd;
    }
}

// ---------------- active-node compaction (wave-coalesced same-address atomics) ----------

__global__ void compact_kernel(const float* __restrict__ nmask, int* __restrict__ alist,
                               int* __restrict__ alcnt, int n) {
    int i = blockIdx.x * 256 + threadIdx.x;
    if (i < n && nmask[i] > 0.f) {
        int pos = atomicAdd(alcnt, 1);
        alist[pos] = i;
    }
}

// ---------------- GEMM (full): out[n][128] = (scale[n] * A[n][128]) @ W[128][128] ------------
// Block 0 passes scale = norm -> xw' = norm*(A@W); agg then needs no per-edge mnorm gather.

__global__ __launch_bounds__(256) void gemm128_kernel(const float* __restrict__ A,
                                                      const float* __restrict__ W,
                                                      const float* __restrict__ gf,
                                                      float* __restrict__ out, int nrows) {
    __shared__ float sT[128][68];
    int row0 = blockIdx.x * 64;
    int tid = threadIdx.x;
    for (int i = tid; i < 2048; i += 256) {
        int r = i >> 5, c4 = i & 31;
        int row = row0 + r;
        float4 v = make_float4(0.f, 0.f, 0.f, 0.f);
        if (row < nrows) {
            float g = gf[row];
            v = ((const float4*)(A + (size_t)row * H))[c4];
            v.x *= g; v.y *= g; v.z *= g; v.w *= g;
        }
        sT[c4 * 4 + 0][r] = v.x; sT[c4 * 4 + 1][r] = v.y;
        sT[c4 * 4 + 2][r] = v.z; sT[c4 * 4 + 3][r] = v.w;
    }
    __syncthreads();
    int cg = tid & 31;
    int rg = tid >> 5;
    float acc[8][4];
#pragma unroll
    for (int i = 0; i < 8; ++i)
#pragma unroll
        for (int j = 0; j < 4; ++j) acc[i][j] = 0.f;

#pragma unroll 4
    for (int k = 0; k < 128; ++k) {
        float4 w4 = ((const float4*)(W + k * H))[cg];
        const float4* pa = (const float4*)(&sT[k][rg * 8]);
        float4 a0 = pa[0], a1 = pa[1];
        float av[8] = {a0.x, a0.y, a0.z, a0.w, a1.x, a1.y, a1.z, a1.w};
#pragma unroll
        for (int i = 0; i < 8; ++i) {
            acc[i][0] = fmaf(av[i], w4.x, acc[i][0]);
            acc[i][1] = fmaf(av[i], w4.y, acc[i][1]);
            acc[i][2] = fmaf(av[i], w4.z, acc[i][2]);
            acc[i][3] = fmaf(av[i], w4.w, acc[i][3]);
        }
    }
#pragma unroll
    for (int i = 0; i < 8; ++i) {
        int row = row0 + rg * 8 + i;
        if (row < nrows) {
            float4 o = make_float4(acc[i][0], acc[i][1], acc[i][2], acc[i][3]);
            ((float4*)(out + (size_t)row * H))[cg] = o;
        }
    }
}

// ---------------- GEMM (compacted rows): only active-list rows ----------------

__global__ __launch_bounds__(256) void gemm128c_kernel(const float* __restrict__ A,
                                                       const float* __restrict__ W,
                                                       const float* __restrict__ gf,
                                                       const int* __restrict__ alist,
                                                       const int* __restrict__ alcnt,
                                                       float* __restrict__ out) {
    int nact = *alcnt;
    int row0 = blockIdx.x * 64;
    if (row0 >= nact) return;
    __shared__ float sT[128][68];
    __shared__ int ridx[64];
    int tid = threadIdx.x;
    if (tid < 64) ridx[tid] = (row0 + tid < nact) ? alist[row0 + tid] : -1;
    __syncthreads();
    for (int i = tid; i < 2048; i += 256) {
        int r = i >> 5, c4 = i & 31;
        int row = ridx[r];
        float4 v = make_float4(0.f, 0.f, 0.f, 0.f);
        if (row >= 0) {
            float g = gf[row];
            v = ((const float4*)(A + (size_t)row * H))[c4];
            v.x *= g; v.y *= g; v.z *= g; v.w *= g;
        }
        sT[c4 * 4 + 0][r] = v.x; sT[c4 * 4 + 1][r] = v.y;
        sT[c4 * 4 + 2][r] = v.z; sT[c4 * 4 + 3][r] = v.w;
    }
    __syncthreads();
    int cg = tid & 31;
    int rg = tid >> 5;
    float acc[8][4];
#pragma unroll
    for (int i = 0; i < 8; ++i)
#pragma unroll
        for (int j = 0; j < 4; ++j) acc[i][j] = 0.f;

#pragma unroll 4
    for (int k = 0; k < 128; ++k) {
        float4 w4 = ((const float4*)(W + k * H))[cg];
        const float4* pa = (const float4*)(&sT[k][rg * 8]);
        float4 a0 = pa[0], a1 = pa[1];
        float av[8] = {a0.x, a0.y, a0.z, a0.w, a1.x, a1.y, a1.z, a1.w};
#pragma unroll
        for (int i = 0; i < 8; ++i) {
            acc[i][0] = fmaf(av[i], w4.x, acc[i][0]);
            acc[i][1] = fmaf(av[i], w4.y, acc[i][1]);
            acc[i][2] = fmaf(av[i], w4.z, acc[i][2]);
            acc[i][3] = fmaf(av[i], w4.w, acc[i][3]);
        }
    }
#pragma unroll
    for (int i = 0; i < 8; ++i) {
        int row = ridx[rg * 8 + i];
        if (row >= 0) {
            float4 o = make_float4(acc[i][0], acc[i][1], acc[i][2], acc[i][3]);
            ((float4*)(out + (size_t)row * H))[cg] = o;
        }
    }
}

// ---------------- fused gather agg + self + bias + relu + score-dot ----------------
// GUARD=false (block 0): xw pre-scaled by norm -> no per-edge scalar gather at all;
//   edge sum * nd, self term = xw'[node]*nd  (== xw[node]*nd^2).
// GUARD=true: xw unscaled; per-edge mnorm gather with skip on zero.

template <bool GUARD>
__global__ __launch_bounds__(256) void agg_fused_kernel(const float* __restrict__ xw,
        const int* __restrict__ rowptr, const int* __restrict__ srcC,
        const float* __restrict__ mask, const float* __restrict__ norm,
        const float* __restrict__ mnorm,
        const float* __restrict__ b, const float* __restrict__ Ws,
        float* __restrict__ hout, float* __restrict__ xws, int n) {
    int node = blockIdx.x * 8 + (threadIdx.x >> 5);
    if (node >= n) return;
    int t = threadIdx.x & 31;
    const float4* xw4 = (const float4*)xw;
    float md = mask[node];
    float nd = norm[node];
    float4 a0 = make_float4(0.f, 0.f, 0.f, 0.f);
    float4 a1 = a0, a2 = a0, a3 = a0;
    if (md != 0.f) {
        int e0 = rowptr[node], e1 = rowptr[node + 1];
        int e = e0;
        for (; e + 3 < e1; e += 4) {
            int s0 = srcC[e], s1 = srcC[e + 1], s2 = srcC[e + 2], s3 = srcC[e + 3];
            if (!GUARD) {
                float4 v0 = xw4[(size_t)s0 * 32 + t];
                float4 v1 = xw4[(size_t)s1 * 32 + t];
                float4 v2 = xw4[(size_t)s2 * 32 + t];
                float4 v3 = xw4[(size_t)s3 * 32 + t];
                a0.x += v0.x; a0.y += v0.y; a0.z += v0.z; a0.w += v0.w;
                a1.x += v1.x; a1.y += v1.y; a1.z += v1.z; a1.w += v1.w;
                a2.x += v2.x; a2.y += v2.y; a2.z += v2.z; a2.w += v2.w;
                a3.x += v3.x; a3.y += v3.y; a3.z += v3.z; a3.w += v3.w;
            } else {
                float c0 = mnorm[s0];
                float c1 = mnorm[s1];
                float c2 = mnorm[s2];
                float c3 = mnorm[s3];
                if (c0 != 0.f) {
                    float4 v = xw4[(size_t)s0 * 32 + t];
                    a0.x = fmaf(v.x, c0, a0.x); a0.y = fmaf(v.y, c0, a0.y);
                    a0.z = fmaf(v.z, c0, a0.z); a0.w = fmaf(v.w, c0, a0.w);
                }
                if (c1 != 0.f) {
                    float4 v = xw4[(size_t)s1 * 32 + t];
                    a1.x = fmaf(v.x, c1, a1.x); a1.y = fmaf(v.y, c1, a1.y);
                    a1.z = fmaf(v.z, c1, a1.z); a1.w = fmaf(v.w, c1, a1.w);
                }
                if (c2 != 0.f) {
                    float4 v = xw4[(size_t)s2 * 32 + t];
                    a2.x = fmaf(v.x, c2, a2.x); a2.y = fmaf(v.y, c2, a2.y);
                    a2.z = fmaf(v.z, c2, a2.z); a2.w = fmaf(v.w, c2, a2.w);
                }
                if (c3 != 0.f) {
                    float4 v = xw4[(size_t)s3 * 32 + t];
                    a3.x = fmaf(v.x, c3, a3.x); a3.y = fmaf(v.y, c3, a3.y);
                    a3.z = fmaf(v.z, c3, a3.z); a3.w = fmaf(v.w, c3, a3.w);
                }
            }
        }
        for (; e < e1; ++e) {
            int s = srcC[e];
            if (!GUARD) {
                float4 v = xw4[(size_t)s * 32 + t];
                a0.x += v.x; a0.y += v.y; a0.z += v.z; a0.w += v.w;
            } else {
                float c = mnorm[s];
                if (c != 0.f) {
                    float4 v = xw4[(size_t)s * 32 + t];
                    a0.x = fmaf(v.x, c, a0.x); a0.y = fmaf(v.y, c, a0.y);
                    a0.z = fmaf(v.z, c, a0.z); a0.w = fmaf(v.w, c, a0.w);
                }
            }
        }
        float sc = md * nd;
        a0.x = (((a0.x + a1.x) + a2.x) + a3.x) * sc;
        a0.y = (((a0.y + a1.y) + a2.y) + a3.y) * sc;
        a0.z = (((a0.z + a1.z) + a2.z) + a3.z) * sc;
        a0.w = (((a0.w + a1.w) + a2.w) + a3.w) * sc;
    }
    float4 self = xw4[(size_t)node * 32 + t];
    float4 bb = ((const float4*)b)[t];
    float selfm = GUARD ? nd * nd : nd;   // !GUARD: xw'[node] = xw[node]*nd already
    float4 v;
    v.x = fmaxf(fmaf(self.x, selfm, a0.x) + bb.x, 0.f);
    v.y = fmaxf(fmaf(self.y, selfm, a0.y) + bb.y, 0.f);
    v.z = fmaxf(fmaf(self.z, selfm, a0.z) + bb.z, 0.f);
    v.w = fmaxf(fmaf(self.w, selfm, a0.w) + bb.w, 0.f);
    ((float4*)hout)[(size_t)node * 32 + t] = v;
    // fused score projection: xws[node] = dot(hout_row, Ws)
    float4 w = ((const float4*)Ws)[t];
    float p = ((v.x * w.x + v.y * w.y) + v.z * w.z) + v.w * w.w;
#pragma unroll
    for (int o = 16; o > 0; o >>= 1) p += __shfl_down(p, o, 32);
    if (t == 0) xws[node] = p;
}

// ---------------- score gather: 8 lanes per node -> masked score (+ zero alcnt) ------------

__global__ void score_gather_kernel(const int* __restrict__ rowptr, const int* __restrict__ srcC,
        const float* __restrict__ xws, const float* __restrict__ mask,
        const float* __restrict__ norm, const float* __restrict__ mnorm,
        const float* __restrict__ bs, float* __restrict__ scorem,
        int* __restrict__ alcnt, int n) {
    int idx = blockIdx.x * 256 + threadIdx.x;
    if (idx == 0) *alcnt = 0;   // consumed earlier this iteration; safe to reset here
    int d = idx >> 3;
    if (d >= n) return;
    int l = idx & 7;
    float md = mask[d];
    float nd = norm[d];
    float acc = 0.f;
    if (md != 0.f) {
        int e0 = rowptr[d], e1 = rowptr[d + 1];
        for (int e = e0 + l; e < e1; e += 8) {
            int s = srcC[e];
            float c = mnorm[s];
            if (c != 0.f) acc = fmaf(xws[s], c, acc);
        }
    }
#pragma unroll
    for (int o = 4; o > 0; o >>= 1) acc += __shfl_down(acc, o, 8);
    if (l == 0) {
        float out;
        if (md != 0.f) out = acc * (md * nd) + xws[d] * nd * nd + bs[0];
        else out = -INFINITY;
        scorem[d] = out;
    }
}

// ---------------- rank-based top-k (kk fused): one 64-lane wave per node ----------------

__global__ __launch_bounds__(256) void rank_kernel(const float* __restrict__ scorem,
        const float* __restrict__ mask, const int* __restrict__ batch,
        const int* __restrict__ starts, const int* __restrict__ counts,
        float* __restrict__ nmask, float* __restrict__ gfac, int n) {
    int i = blockIdx.x * 4 + (threadIdx.x >> 6);
    if (i >= n) return;
    int lane = threadIdx.x & 63;
    float sci = scorem[i];
    if (sci == -INFINITY) {
        if (lane == 0) { nmask[i] = 0.f; gfac[i] = 0.f; }
        return;
    }
    int g = batch[i];
    int s0 = starts[g], cnt = counts[g];
    int r = 0, act = 0;
    for (int j = lane; j < cnt; j += 64) {
        float sj = scorem[s0 + j];
        if (sj != -INFINITY) {
            ++act;
            if (sj > sci || (sj == sci && (s0 + j) < i)) ++r;
        }
    }
#pragma unroll
    for (int o = 32; o > 0; o >>= 1) {
        r += __shfl_down(r, o);
        act += __shfl_down(act, o);
    }
    if (lane == 0) {
        int kk = (int)ceilf(0.5f * (float)act);
        bool keep = (r < kk);
        float m = mask[i];
        nmask[i] = keep ? m : 0.f;
        gfac[i] = keep ? tanhf(sci) * m : 0.f;
    }
}

// ---------------- readout phase 1: per-(graph, sub-slice) partials ----------------

__global__ __launch_bounds__(128) void readout_part_kernel(const float* __restrict__ h,
        const float* __restrict__ mask, const float* __restrict__ gfac,
        const int* __restrict__ starts, const int* __restrict__ counts,
        float* __restrict__ partS, float* __restrict__ partM, float* __restrict__ partC) {
    int g = blockIdx.x >> 4;
    int sub = blockIdx.x & (RSUB - 1);
    int f = threadIdx.x;
    int s0 = starts[g], cnt = counts[g];
    float s = 0.f, mx = -INFINITY, c = 0.f;
    for (int i = sub; i < cnt; i += RSUB) {
        float m = mask[s0 + i];
        if (m > 0.f) {
            float v = h[(size_t)(s0 + i) * H + f] * gfac[s0 + i];
            s += v; mx = fmaxf(mx, v); c += 1.f;
        }
    }
    size_t pidx = (size_t)blockIdx.x * H + f;
    partS[pidx] = s;
    partM[pidx] = mx;
    if (f == 0) partC[blockIdx.x] = c;
}

// ---------------- readout phase 2: combine partials; store on blk0, accumulate after --------

__global__ __launch_bounds__(128) void readout_comb_kernel(const float* __restrict__ partS,
        const float* __restrict__ partM, const float* __restrict__ partC,
        float* __restrict__ r, int accum) {
    int g = blockIdx.x;
    int f = threadIdx.x;
    float S = 0.f, M = -INFINITY, C = 0.f;
    for (int sub = 0; sub < RSUB; ++sub) {
        size_t pidx = (size_t)(g * RSUB + sub) * H + f;
        S += partS[pidx];
        M = fmaxf(M, partM[pidx]);
        C += partC[g * RSUB + sub];
    }
    float mean = S / fmaxf(C, 1.f);
    if (C == 0.f) M = 0.f;
    if (accum) {
        r[(size_t)g * 2 * H + f] += M;
        r[(size_t)g * 2 * H + H + f] += mean;
    } else {
        r[(size_t)g * 2 * H + f] = M;
        r[(size_t)g * 2 * H + H + f] = mean;
    }
}

// ---------------- MLP head + log_softmax ----------------

__global__ __launch_bounds__(128) void mlp_kernel(const float* __restrict__ r,
        const float* __restrict__ Wl1, const float* __restrict__ bl1,
        const float* __restrict__ Wl2, const float* __restrict__ bl2,
        const float* __restrict__ Wl3, const float* __restrict__ bl3,
        float* __restrict__ out) {
    int g = blockIdx.x;
    int t = threadIdx.x;
    __shared__ float sz[256];
    __shared__ float sy1[128];
    __shared__ float sy2[64];
    __shared__ float sy3[10];
    __shared__ float sred[2];
    sz[t] = r[g * 256 + t];
    sz[t + 128] = r[g * 256 + 128 + t];
    __syncthreads();
    float a = bl1[t];
    for (int k = 0; k < 256; ++k) a = fmaf(sz[k], Wl1[k * 128 + t], a);
    sy1[t] = fmaxf(a, 0.f);
    __syncthreads();
    if (t < 64) {
        float a2 = bl2[t];
        for (int k = 0; k < 128; ++k) a2 = fmaf(sy1[k], Wl2[k * 64 + t], a2);
        sy2[t] = fmaxf(a2, 0.f);
    }
    __syncthreads();
    if (t < 10) {
        float a3 = bl3[t];
        for (int k = 0; k < 64; ++k) a3 = fmaf(sy2[k], Wl3[k * 10 + t], a3);
        sy3[t] = a3;
    }
    __syncthreads();
    if (t == 0) {
        float m = sy3[0];
        for (int c2 = 1; c2 < 10; ++c2) m = fmaxf(m, sy3[c2]);
        float se = 0.f;
        for (int c2 = 0; c2 < 10; ++c2) se += expf(sy3[c2] - m);
        sred[0] = m; sred[1] = logf(se);
    }
    __syncthreads();
    if (t < 10) out[g * 10 + t] = sy3[t] - sred[0] - sred[1];
}

// ---------------- launch ----------------

extern "C" void kernel_launch(void* const* d_in, const int* in_sizes, int n_in,
                              void* d_out, int out_size, void* d_ws, size_t ws_size,
                              hipStream_t stream) {
    const float* x     = (const float*)d_in[0];
    const int*   ei    = (const int*)d_in[1];
    const int*   batch = (const int*)d_in[2];
    const int* src  = ei;
    const int* dstp = ei + N_EDGES;
    const float* Wb[3]  = {(const float*)d_in[3], (const float*)d_in[7],  (const float*)d_in[11]};
    const float* bbv[3] = {(const float*)d_in[4], (const float*)d_in[8],  (const float*)d_in[12]};
    const float* Wsb[3] = {(const float*)d_in[5], (const float*)d_in[9],  (const float*)d_in[13]};
    const float* bsb[3] = {(const float*)d_in[6], (const float*)d_in[10], (const float*)d_in[14]};
    const float* Wl1 = (const float*)d_in[15];
    const float* bl1 = (const float*)d_in[16];
    const float* Wl2 = (const float*)d_in[17];
    const float* bl2 = (const float*)d_in[18];
    const float* Wl3 = (const float*)d_in[19];
    const float* bl3 = (const float*)d_in[20];
    float* out = (float*)d_out;

    // workspace carve (4B units)
    float* fws = (float*)d_ws;
    size_t off = 0;
    float* hA     = fws + off; off += (size_t)N_NODES * H;
    float* hB     = fws + off; off += (size_t)N_NODES * H;
    float* xw     = fws + off; off += (size_t)N_NODES * H;
    float* scorem = fws + off; off += N_NODES;
    float* xws    = fws + off; off += N_NODES;
    float* norm   = fws + off; off += N_NODES;
    float* mnorm  = fws + off; off += N_NODES;
    float* mA     = fws + off; off += N_NODES;
    float* mB     = fws + off; off += N_NODES;
    float* gfac   = fws + off; off += N_NODES;
    float* rbuf   = fws + off; off += (size_t)G_GRAPHS * 2 * H;
    float* partS  = fws + off; off += (size_t)G_GRAPHS * RSUB * H;
    float* partM  = fws + off; off += (size_t)G_GRAPHS * RSUB * H;
    float* partC  = fws + off; off += (size_t)G_GRAPHS * RSUB;
    int* counts   = (int*)(fws + off); off += G_GRAPHS;
    int* starts   = (int*)(fws + off); off += G_GRAPHS;
    int* rowptr   = (int*)(fws + off); off += N_NODES + 1;
    int* indeg    = (int*)(fws + off); off += N_NODES;
    int* cursor   = (int*)(fws + off); off += N_NODES;
    int* bsum     = (int*)(fws + off); off += NBLK_SCAN;
    int* boff     = (int*)(fws + off); off += NBLK_SCAN;
    int* alist    = (int*)(fws + off); off += N_NODES;
    int* alcnt    = (int*)(fws + off); off += 1;
    int* srcC     = (int*)(fws + off); off += N_EDGES;

    int nblkN  = (N_NODES + 255) / 256;
    int nblkN8 = (N_NODES * 8 + 255) / 256;
    int nblkE  = (N_EDGES + 255) / 256;
    int nblkG  = (N_NODES + 63) / 64;

    // combined init (starts + zero indeg/cursor + mA/gfac = 1), then counts
    init_kernel<<<nblkN, 256, 0, stream>>>(batch, starts, indeg, cursor, mA, gfac, N_NODES);
    counts_kernel<<<1, 128, 0, stream>>>(starts, counts);

    // CSR build (dst-grouped), deterministic via per-node wave sort
    indeg_kernel<<<nblkE, 256, 0, stream>>>(dstp, indeg, N_EDGES);
    bsum_kernel<<<NBLK_SCAN, 256, 0, stream>>>(indeg, bsum, N_NODES);
    bscan_kernel<<<1, 256, 0, stream>>>(bsum, boff, NBLK_SCAN);
    rowptr_kernel<<<NBLK_SCAN, 256, 0, stream>>>(indeg, boff, rowptr, N_NODES);
    scatter_kernel<<<nblkE, 256, 0, stream>>>(src, dstp, rowptr, cursor, srcC, N_EDGES);
    wsort_kernel<<<(N_NODES + 3) / 4, 256, 0, stream>>>(rowptr, srcC, N_NODES);

    const float* hin = x;
    float* hout = hA;
    const float* mcur = mA;
    float* mnext = mB;

    for (int blk = 0; blk < 3; ++blk) {
        if (blk == 0) {
            degnorm0_kernel<<<nblkN, 256, 0, stream>>>(indeg, norm, mnorm, N_NODES);
            // xw' = norm * (A @ W)  (gfac==1; scale by norm so agg needs no mnorm gather)
            gemm128_kernel<<<nblkG, 256, 0, stream>>>(hin, Wb[blk], norm, xw, N_NODES);
            agg_fused_kernel<false><<<(N_NODES + 7) / 8, 256, 0, stream>>>(
                xw, rowptr, srcC, mcur, norm, mnorm, bbv[blk], Wsb[blk], hout, xws, N_NODES);
        } else {
            degnorm_kernel<<<nblkN8, 256, 0, stream>>>(rowptr, srcC, mcur, norm, mnorm, N_NODES);
            gemm128c_kernel<<<nblkG, 256, 0, stream>>>(hin, Wb[blk], gfac, alist, alcnt, xw);
            agg_fused_kernel<true><<<(N_NODES + 7) / 8, 256, 0, stream>>>(
                xw, rowptr, srcC, mcur, norm, mnorm, bbv[blk], Wsb[blk], hout, xws, N_NODES);
        }
        score_gather_kernel<<<nblkN8, 256, 0, stream>>>(rowptr, srcC, xws, mcur, norm, mnorm,
                                                        bsb[blk], scorem, alcnt, N_NODES);
        rank_kernel<<<(N_NODES + 3) / 4, 256, 0, stream>>>(scorem, mcur, batch, starts, counts,
                                                           mnext, gfac, N_NODES);
        if (blk < 2) {
            compact_kernel<<<nblkN, 256, 0, stream>>>(mnext, alist, alcnt, N_NODES);
        }
        readout_part_kernel<<<G_GRAPHS * RSUB, 128, 0, stream>>>(hout, mnext, gfac, starts,
                                                                 counts, partS, partM, partC);
        readout_comb_kernel<<<G_GRAPHS, 128, 0, stream>>>(partS, partM, partC, rbuf, blk);
        hin = hout;
        hout = (hout == hA) ? hB : hA;
        const float* tm = mcur; mcur = mnext; mnext = (float*)tm;
    }

    mlp_kernel<<<G_GRAPHS, 128, 0, stream>>>(rbuf, Wl1, bl1, Wl2, bl2, Wl3, bl3, out);
}